// Round 2
// baseline (900.466 us; speedup 1.0000x reference)
//
#include <hip/hip_runtime.h>
#include <float.h>

#define N4K 4096
#define NP1 4097

typedef __attribute__((ext_vector_type(4))) float f32x4;
typedef __attribute__((ext_vector_type(8))) short bf16x8;

__device__ __forceinline__ unsigned short f2bf(float x) {
    union { float f; unsigned int u; } v; v.f = x;
    unsigned int r = v.u + 0x7FFFu + ((v.u >> 16) & 1u);   // round-nearest-even
    return (unsigned short)(r >> 16);
}

__device__ __forceinline__ void gload_lds16(const void* g, void* l) {
    __builtin_amdgcn_global_load_lds(
        (const __attribute__((address_space(1))) unsigned int*)g,
        (__attribute__((address_space(3))) unsigned int*)l,
        16, 0, 0);
}

// ---- prep: W2_{lb,ub} fp32 [4096][4097] -> bf16 [2][4096][4096] (drop bias col)
__global__ __launch_bounds__(256) void prep_A(const float* __restrict__ W2lb,
                                              const float* __restrict__ W2ub,
                                              unsigned short* __restrict__ Abf) {
    const long long total = 2LL * N4K * N4K;
    for (long long idx = (long long)blockIdx.x * 256 + threadIdx.x; idx < total;
         idx += (long long)gridDim.x * 256) {
        int mat = (int)(idx >> 24);
        int rem = (int)(idx & 0xFFFFFF);
        int i = rem >> 12, k = rem & 4095;
        const float* src = mat ? W2ub : W2lb;
        Abf[idx] = f2bf(src[(long long)i * NP1 + k]);
    }
}

// ---- prep: build M^T, D^T bf16 [4096 j][4096 k] via LDS tile transpose
__global__ __launch_bounds__(256) void prep_B(const float* __restrict__ W1lb,
                                              const float* __restrict__ W1ub,
                                              unsigned short* __restrict__ Bmt,
                                              unsigned short* __restrict__ Bdt) {
    __shared__ unsigned short Lm[64 * 65];
    __shared__ unsigned short Ld[64 * 65];
    int j0 = blockIdx.x * 64, k0 = blockIdx.y * 64;
    int t = threadIdx.x;
    int jj = t & 63, kkb = t >> 6;
#pragma unroll 4
    for (int p = 0; p < 16; ++p) {
        int kk = kkb + p * 4;
        long long off = (long long)(k0 + kk) * NP1 + j0 + jj;
        float l = W1lb[off], u = W1ub[off];
        Lm[kk * 65 + jj] = f2bf(0.5f * (l + u));
        Ld[kk * 65 + jj] = f2bf(0.5f * (u - l));
    }
    __syncthreads();
#pragma unroll
    for (int p = 0; p < 2; ++p) {
        int jl = p * 32 + (t >> 3);
        int kl = (t & 7) * 8;
        bf16x8 vm, vd;
#pragma unroll
        for (int i = 0; i < 8; ++i) {
            vm[i] = (short)Lm[(kl + i) * 65 + jl];
            vd[i] = (short)Ld[(kl + i) * 65 + jl];
        }
        *(bf16x8*)&Bmt[(long long)(j0 + jl) * N4K + k0 + kl] = vm;
        *(bf16x8*)&Bdt[(long long)(j0 + jl) * N4K + k0 + kl] = vd;
    }
}

// ---- prep: bias column of W1 -> mb, db (fp32)
__global__ __launch_bounds__(256) void prep_mbdb(const float* __restrict__ W1lb,
                                                 const float* __restrict__ W1ub,
                                                 float* __restrict__ mb,
                                                 float* __restrict__ db) {
    int k = blockIdx.x * 256 + threadIdx.x;
    if (k < N4K) {
        float l = W1lb[(long long)k * NP1 + 4096];
        float u = W1ub[(long long)k * NP1 + 4096];
        mb[k] = 0.5f * (l + u);
        db[k] = 0.5f * (u - l);
    }
}

// ---- fused GEMM: cur = A@M ± |A|@D, reduced over j against (m[j], d[j]) into prev[8192]
__global__ __launch_bounds__(256) void gemm_fused(const unsigned short* __restrict__ Abf,
                                                  const unsigned short* __restrict__ Bmt,
                                                  const unsigned short* __restrict__ Bdt,
                                                  const float* __restrict__ lb0,
                                                  const float* __restrict__ ub0,
                                                  float* __restrict__ prev) {
    __shared__ unsigned short As[128 * 32];
    __shared__ unsigned short Bms[128 * 32];
    __shared__ unsigned short Bds[128 * 32];

    // XCD-aware swizzle of the flat tile id (2048 tiles, divisible by 8)
    int wg = blockIdx.y * gridDim.x + blockIdx.x;
    int nwg = gridDim.x * gridDim.y;
    int swz = (wg & 7) * (nwg >> 3) + (wg >> 3);
    int bx = swz & 31;        // col tile 0..31
    int by = swz >> 5;        // row tile 0..63

    int is_ub = by >> 5;
    long long arow0 = (long long)(by & 31) * 128;
    const unsigned short* Aptr = Abf + ((long long)is_ub << 24) + arow0 * N4K;
    int col0 = bx * 128;
    const unsigned short* Bmp = Bmt + (long long)col0 * N4K;
    const unsigned short* Bdp = Bdt + (long long)col0 * N4K;

    int tid = threadIdx.x;
    int lane = tid & 63, wid = tid >> 6;
    int wr = wid >> 1, wc = wid & 1;
    int la = lane & 15, lk = (lane >> 4) * 8;

    // staging maps: thread tid loads 16B: row tid/4, col (tid&3)*8; lds linear 16B/thread
    int sr = tid >> 2;
    int sc = (tid & 3) * 8;

    f32x4 acc[4][4];
#pragma unroll
    for (int m = 0; m < 4; ++m)
#pragma unroll
        for (int n = 0; n < 4; ++n) acc[m][n] = (f32x4){0.f, 0.f, 0.f, 0.f};

    for (int kt = 0; kt < 128; ++kt) {
        int k0 = kt * 32;
#pragma unroll
        for (int r = 0; r < 2; ++r) {
            long long go = (long long)(sr + r * 64) * N4K + k0 + sc;
            unsigned lo = (unsigned)(r * 2048 + wid * 512);
            gload_lds16(Aptr + go, &As[lo]);
            gload_lds16(Bmp + go, &Bms[lo]);
            gload_lds16(Bdp + go, &Bds[lo]);
        }
        __syncthreads();

        bf16x8 af[4], am[4], bmf[4], bdf[4];
#pragma unroll
        for (int m = 0; m < 4; ++m)
            af[m] = *(const bf16x8*)&As[(wr * 64 + m * 16 + la) * 32 + lk];
#pragma unroll
        for (int n = 0; n < 4; ++n) {
            bmf[n] = *(const bf16x8*)&Bms[(wc * 64 + n * 16 + la) * 32 + lk];
            bdf[n] = *(const bf16x8*)&Bds[(wc * 64 + n * 16 + la) * 32 + lk];
        }
        if (is_ub) {
#pragma unroll
            for (int m = 0; m < 4; ++m) am[m] = af[m] & (short)0x7FFF;   // +|x|
        } else {
#pragma unroll
            for (int m = 0; m < 4; ++m) am[m] = af[m] | (short)0x8000;   // -|x|
        }
#pragma unroll
        for (int m = 0; m < 4; ++m)
#pragma unroll
            for (int n = 0; n < 4; ++n) {
                acc[m][n] = __builtin_amdgcn_mfma_f32_16x16x32_bf16(af[m], bmf[n], acc[m][n], 0, 0, 0);
                acc[m][n] = __builtin_amdgcn_mfma_f32_16x16x32_bf16(am[m], bdf[n], acc[m][n], 0, 0, 0);
            }
        __syncthreads();
    }

    // fused second backsub stage: rowpart[i] = sum_j v*m[j] + s*d[j]*|v|
    float s = is_ub ? 1.f : -1.f;
    float rowpart[4][4];
#pragma unroll
    for (int m = 0; m < 4; ++m)
#pragma unroll
        for (int r = 0; r < 4; ++r) rowpart[m][r] = 0.f;

    int jbase = col0 + wc * 64;
#pragma unroll
    for (int n = 0; n < 4; ++n) {
        int j = jbase + n * 16 + la;
        float l0 = lb0[j], u0 = ub0[j];
        float mj = 0.5f * (l0 + u0);
        float sdj = s * 0.5f * (u0 - l0);
#pragma unroll
        for (int m = 0; m < 4; ++m)
#pragma unroll
            for (int r = 0; r < 4; ++r) {
                float v = acc[m][n][r];
                rowpart[m][r] += v * mj + sdj * fabsf(v);
            }
    }
    long long rowg = (long long)by * 128 + wr * 64 + (lane >> 4) * 4;
#pragma unroll
    for (int m = 0; m < 4; ++m)
#pragma unroll
        for (int r = 0; r < 4; ++r) {
            float v = rowpart[m][r];
            v += __shfl_xor(v, 1);
            v += __shfl_xor(v, 2);
            v += __shfl_xor(v, 4);
            v += __shfl_xor(v, 8);
            if (la == 0) atomicAdd(&prev[rowg + m * 16 + r], v);
        }
}

// ---- bias-column matvec (fp32, exact): prev[i] += sum_k W2[i,k]*mb[k] + s*db[k]*|W2[i,k]| + W2[i,4096]
__global__ __launch_bounds__(256) void matvec_bias(const float* __restrict__ W2lb,
                                                   const float* __restrict__ W2ub,
                                                   const float* __restrict__ mb,
                                                   const float* __restrict__ db,
                                                   float* __restrict__ prev) {
    int b = blockIdx.x;                 // 0..8191
    int chain = b >> 12, i = b & 4095;
    const float* row = (chain ? W2ub : W2lb) + (long long)i * NP1;
    float s = chain ? 1.f : -1.f;
    float part = 0.f;
    for (int k = threadIdx.x; k < N4K; k += 256) {
        float w = row[k];
        part += w * mb[k] + s * db[k] * fabsf(w);
    }
    __shared__ float red[4];
#pragma unroll
    for (int off = 32; off; off >>= 1) part += __shfl_down(part, off);
    if ((threadIdx.x & 63) == 0) red[threadIdx.x >> 6] = part;
    __syncthreads();
    if (threadIdx.x == 0) {
        float tot = red[0] + red[1] + red[2] + red[3] + row[4096];
        atomicAdd(&prev[b], tot);
    }
}

// ---- epilogue: PReLU relaxation, scatter diag + bias col
__global__ __launch_bounds__(256) void epilogue(const float* __restrict__ prev,
                                                const float* __restrict__ alphas,
                                                float* __restrict__ out) {
    int i = blockIdx.x * 256 + threadIdx.x;
    if (i >= N4K) return;
    float lb = prev[i], ub = prev[N4K + i];
    float a = fminf(fmaxf(alphas[i], 0.f), 1.f);
    if (lb > 0.f) a = 1.f;
    if (ub <= 0.f) a = 0.f;
    float slope = ub / (ub - lb + FLT_EPSILON);
    if (lb > 0.f) slope = 1.f;
    if (ub < 0.f) slope = 0.f;
    float bias = -lb * slope;
    if (lb > 0.f || ub < 0.f) bias = 0.f;
    long long P = NP1, half = (long long)N4K * NP1;
    out[(long long)i * P + i] = a;
    out[half + (long long)i * P + i] = slope;
    out[half + (long long)i * P + 4096] = bias;
}

extern "C" void kernel_launch(void* const* d_in, const int* in_sizes, int n_in,
                              void* d_out, int out_size, void* d_ws, size_t ws_size,
                              hipStream_t stream) {
    const float* lb0    = (const float*)d_in[0];
    const float* ub0    = (const float*)d_in[1];
    const float* W1lb   = (const float*)d_in[2];
    const float* W1ub   = (const float*)d_in[3];
    const float* W2lb   = (const float*)d_in[4];
    const float* W2ub   = (const float*)d_in[5];
    const float* alphas = (const float*)d_in[6];

    char* ws = (char*)d_ws;
    float* prev = (float*)ws;                                    // 32768 B
    float* mb   = (float*)(ws + 32768);                          // 16384 B
    float* db   = (float*)(ws + 49152);                          // 16384 B
    unsigned short* Abf = (unsigned short*)(ws + 65536);         // 64 MiB
    unsigned short* Bmt = (unsigned short*)(ws + 65536 + 67108864);   // 32 MiB
    unsigned short* Bdt = (unsigned short*)(ws + 65536 + 100663296);  // 32 MiB
    size_t need = 65536ULL + 67108864ULL + 2ULL * 33554432ULL;   // ~128 MiB
    if (ws_size < need) return;  // visible failure if ws too small

    (void)hipMemsetAsync(prev, 0, 32768, stream);
    (void)hipMemsetAsync(d_out, 0, (size_t)out_size * 4, stream);

    prep_A<<<4096, 256, 0, stream>>>(W2lb, W2ub, Abf);
    prep_B<<<dim3(64, 64), 256, 0, stream>>>(W1lb, W1ub, Bmt, Bdt);
    prep_mbdb<<<16, 256, 0, stream>>>(W1lb, W1ub, mb, db);
    gemm_fused<<<dim3(32, 64), 256, 0, stream>>>(Abf, Bmt, Bdt, lb0, ub0, prev);
    matvec_bias<<<8192, 256, 0, stream>>>(W2lb, W2ub, mb, db, (float*)prev);
    epilogue<<<16, 256, 0, stream>>>(prev, alphas, (float*)d_out);
}

// Round 3
// 716.453 us; speedup vs baseline: 1.2568x; 1.2568x over previous
//
#include <hip/hip_runtime.h>
#include <float.h>

#define N4K 4096
#define NP1 4097

typedef __attribute__((ext_vector_type(4))) float f32x4;
typedef __attribute__((ext_vector_type(8))) short bf16x8;

__device__ __forceinline__ unsigned short f2bf(float x) {
    union { float f; unsigned int u; } v; v.f = x;
    unsigned int r = v.u + 0x7FFFu + ((v.u >> 16) & 1u);   // round-nearest-even
    return (unsigned short)(r >> 16);
}

__device__ __forceinline__ void gload_lds16(const void* g, void* l) {
    __builtin_amdgcn_global_load_lds(
        (const __attribute__((address_space(1))) unsigned int*)g,
        (__attribute__((address_space(3))) unsigned int*)l,
        16, 0, 0);
}

__device__ __forceinline__ void bar() {
    asm volatile("" ::: "memory");
    __builtin_amdgcn_s_barrier();
    asm volatile("" ::: "memory");
}

// ---- prep: W2 row -> bf16 cast + fused bias-matvec (replaces prep_A + matvec_bias)
__global__ __launch_bounds__(256) void prep_A2(const float* __restrict__ W2lb,
                                               const float* __restrict__ W2ub,
                                               const float* __restrict__ mb,
                                               const float* __restrict__ db,
                                               unsigned short* __restrict__ Abf,
                                               float* __restrict__ prev) {
    int b = blockIdx.x;                 // 0..8191
    int chain = b >> 12, i = b & 4095;
    const float* row = (chain ? W2ub : W2lb) + (long long)i * NP1;
    unsigned short* abf_row = Abf + ((long long)chain << 24) + (long long)i * N4K;
    float s = chain ? 1.f : -1.f;
    float part = 0.f;
#pragma unroll 4
    for (int p = 0; p < 16; ++p) {
        int k = threadIdx.x + p * 256;
        float wv = row[k];
        abf_row[k] = f2bf(wv);
        part += wv * mb[k] + s * db[k] * fabsf(wv);
    }
    __shared__ float red[4];
#pragma unroll
    for (int off = 32; off; off >>= 1) part += __shfl_down(part, off);
    if ((threadIdx.x & 63) == 0) red[threadIdx.x >> 6] = part;
    __syncthreads();
    if (threadIdx.x == 0)
        prev[b] = red[0] + red[1] + red[2] + red[3] + row[4096];
}

// ---- prep: build M^T, D^T bf16 [4096 j][4096 k] via LDS tile transpose
__global__ __launch_bounds__(256) void prep_B(const float* __restrict__ W1lb,
                                              const float* __restrict__ W1ub,
                                              unsigned short* __restrict__ Bmt,
                                              unsigned short* __restrict__ Bdt) {
    __shared__ unsigned short Lm[64 * 65];
    __shared__ unsigned short Ld[64 * 65];
    int j0 = blockIdx.x * 64, k0 = blockIdx.y * 64;
    int t = threadIdx.x;
    int jj = t & 63, kkb = t >> 6;
#pragma unroll 4
    for (int p = 0; p < 16; ++p) {
        int kk = kkb + p * 4;
        long long off = (long long)(k0 + kk) * NP1 + j0 + jj;
        float l = W1lb[off], u = W1ub[off];
        Lm[kk * 65 + jj] = f2bf(0.5f * (l + u));
        Ld[kk * 65 + jj] = f2bf(0.5f * (u - l));
    }
    __syncthreads();
#pragma unroll
    for (int p = 0; p < 2; ++p) {
        int jl = p * 32 + (t >> 3);
        int kl = (t & 7) * 8;
        bf16x8 vm, vd;
#pragma unroll
        for (int i = 0; i < 8; ++i) {
            vm[i] = (short)Lm[(kl + i) * 65 + jl];
            vd[i] = (short)Ld[(kl + i) * 65 + jl];
        }
        *(bf16x8*)&Bmt[(long long)(j0 + jl) * N4K + k0 + kl] = vm;
        *(bf16x8*)&Bdt[(long long)(j0 + jl) * N4K + k0 + kl] = vd;
    }
}

// ---- prep: bias column of W1 -> mb, db (fp32)
__global__ __launch_bounds__(256) void prep_mbdb(const float* __restrict__ W1lb,
                                                 const float* __restrict__ W1ub,
                                                 float* __restrict__ mb,
                                                 float* __restrict__ db) {
    int k = blockIdx.x * 256 + threadIdx.x;
    if (k < N4K) {
        float l = W1lb[(long long)k * NP1 + 4096];
        float u = W1ub[(long long)k * NP1 + 4096];
        mb[k] = 0.5f * (l + u);
        db[k] = 0.5f * (u - l);
    }
}

// ---- fused GEMM, phase-pipelined: 256x128 tile, BK=64, 8 waves, counted vmcnt
__global__ __launch_bounds__(512, 2) void gemm_fused(const unsigned short* __restrict__ Abf,
                                                     const unsigned short* __restrict__ Bmt,
                                                     const unsigned short* __restrict__ Bdt,
                                                     const float* __restrict__ lb0,
                                                     const float* __restrict__ ub0,
                                                     float* __restrict__ prev) {
    __shared__ unsigned short As[2][16384];   // 256x64 bf16, dbuf
    __shared__ unsigned short Bms[2][8192];   // 128x64
    __shared__ unsigned short Bds[2][8192];

    // XCD-aware bijective swizzle (1024 blocks % 8 == 0)
    int wg = blockIdx.x;
    int swz = (wg & 7) * 128 + (wg >> 3);
    int rt = swz & 31;          // row tile (0..31): 16 lb + 16 ub
    int ct = swz >> 5;          // col tile (0..31)

    int chain = rt >> 4;
    const unsigned short* Aptr = Abf + ((long long)chain << 24) + (long long)(rt & 15) * 256 * N4K;
    const unsigned short* Bmp = Bmt + (long long)ct * 128 * N4K;
    const unsigned short* Bdp = Bdt + (long long)ct * 128 * N4K;

    int tid = threadIdx.x;
    int lane = tid & 63, w = tid >> 6;
    int wr = w >> 1, wc = w & 1;              // 4M x 2N waves, 64x64 per wave
    int la = lane & 15, kq = lane >> 4;
    int x7 = la & 7;

    // staging source map (pre-swizzled global column; linear LDS dest)
    int srow = tid >> 3;                           // 0..63
    int sce = ((tid & 7) ^ (srow & 7)) << 3;       // swizzled element offset in row
    const unsigned short* aS = Aptr + (long long)srow * N4K + sce;
    const unsigned short* mS = Bmp + (long long)srow * N4K + sce;
    const unsigned short* dS = Bdp + (long long)srow * N4K + sce;
    const long long R64 = 64LL * N4K;
    unsigned ldst = w * 512;                       // wave-uniform LDS base (shorts)

    int arow = wr * 64 + la;
    int brow = wc * 64 + la;

    f32x4 acc[4][4];
#pragma unroll
    for (int m = 0; m < 4; ++m)
#pragma unroll
        for (int n = 0; n < 4; ++n) acc[m][n] = (f32x4){0.f, 0.f, 0.f, 0.f};

    // prologue: stage tile 0 fully, drain, barrier
#pragma unroll
    for (int q = 0; q < 4; ++q) gload_lds16(aS + q * R64, &As[0][q * 4096 + ldst]);
#pragma unroll
    for (int q = 0; q < 2; ++q) gload_lds16(mS + q * R64, &Bms[0][q * 4096 + ldst]);
#pragma unroll
    for (int q = 0; q < 2; ++q) gload_lds16(dS + q * R64, &Bds[0][q * 4096 + ldst]);
    asm volatile("s_waitcnt vmcnt(0)" ::: "memory");
    bar();

#define FRAG(arr, cur, rb, f, k) \
    (*(const bf16x8*)&arr[cur][((rb) + (f) * 16) * 64 + ((((k) * 4 + kq) ^ x7) * 8)])

#pragma unroll 1
    for (int t = 0; t < 64; ++t) {
        const int cur = t & 1, nxt = cur ^ 1;
        const int k0n = (t + 1) * 64;
        const bool pf = (t < 63);

        bf16x8 af[4][2], ax[4][2], bd0[2][2], bd1[2][2], bm0[2][2], bm1[2][2];

        // ===== phase 0: A frags + Bd(n0,n1); stage Bd'; MFMA D(n0,n1)
#pragma unroll
        for (int m = 0; m < 4; ++m)
#pragma unroll
            for (int k = 0; k < 2; ++k) af[m][k] = FRAG(As, cur, arow, m, k);
#pragma unroll
        for (int n = 0; n < 2; ++n)
#pragma unroll
            for (int k = 0; k < 2; ++k) bd0[n][k] = FRAG(Bds, cur, brow, n, k);
#pragma unroll
        for (int m = 0; m < 4; ++m)
#pragma unroll
            for (int k = 0; k < 2; ++k)
                ax[m][k] = chain ? (af[m][k] & (short)0x7FFF) : (af[m][k] | (short)0x8000);
        if (pf) {
            gload_lds16(dS + k0n, &Bds[nxt][ldst]);
            gload_lds16(dS + R64 + k0n, &Bds[nxt][4096 + ldst]);
        }
        bar();
        __builtin_amdgcn_s_setprio(1);
#pragma unroll
        for (int m = 0; m < 4; ++m)
#pragma unroll
            for (int n = 0; n < 2; ++n)
#pragma unroll
                for (int k = 0; k < 2; ++k)
                    acc[m][n] = __builtin_amdgcn_mfma_f32_16x16x32_bf16(ax[m][k], bd0[n][k], acc[m][n], 0, 0, 0);
        __builtin_amdgcn_s_setprio(0);
        bar();

        // ===== phase 1: Bd(n2,n3); stage A'lo; MFMA D(n2,n3); mid-tile wait
#pragma unroll
        for (int n = 0; n < 2; ++n)
#pragma unroll
            for (int k = 0; k < 2; ++k) bd1[n][k] = FRAG(Bds, cur, brow, n + 2, k);
        if (pf) {
            gload_lds16(aS + k0n, &As[nxt][ldst]);
            gload_lds16(aS + R64 + k0n, &As[nxt][4096 + ldst]);
        }
        bar();
        __builtin_amdgcn_s_setprio(1);
#pragma unroll
        for (int m = 0; m < 4; ++m)
#pragma unroll
            for (int n = 0; n < 2; ++n)
#pragma unroll
                for (int k = 0; k < 2; ++k)
                    acc[m][n + 2] = __builtin_amdgcn_mfma_f32_16x16x32_bf16(ax[m][k], bd1[n][k], acc[m][n + 2], 0, 0, 0);
        __builtin_amdgcn_s_setprio(0);
        if (pf) asm volatile("s_waitcnt vmcnt(4)" ::: "memory");   // drain current tile's Bm
        else    asm volatile("s_waitcnt vmcnt(0)" ::: "memory");
        bar();

        // ===== phase 2: Bm(n0,n1); stage A'hi; MFMA M(n0,n1)
#pragma unroll
        for (int n = 0; n < 2; ++n)
#pragma unroll
            for (int k = 0; k < 2; ++k) bm0[n][k] = FRAG(Bms, cur, brow, n, k);
        if (pf) {
            gload_lds16(aS + 2 * R64 + k0n, &As[nxt][8192 + ldst]);
            gload_lds16(aS + 3 * R64 + k0n, &As[nxt][12288 + ldst]);
        }
        bar();
        __builtin_amdgcn_s_setprio(1);
#pragma unroll
        for (int m = 0; m < 4; ++m)
#pragma unroll
            for (int n = 0; n < 2; ++n)
#pragma unroll
                for (int k = 0; k < 2; ++k)
                    acc[m][n] = __builtin_amdgcn_mfma_f32_16x16x32_bf16(af[m][k], bm0[n][k], acc[m][n], 0, 0, 0);
        __builtin_amdgcn_s_setprio(0);
        bar();

        // ===== phase 3: Bm(n2,n3); stage Bm'; MFMA M(n2,n3); boundary wait
#pragma unroll
        for (int n = 0; n < 2; ++n)
#pragma unroll
            for (int k = 0; k < 2; ++k) bm1[n][k] = FRAG(Bms, cur, brow, n + 2, k);
        if (pf) {
            gload_lds16(mS + k0n, &Bms[nxt][ldst]);
            gload_lds16(mS + R64 + k0n, &Bms[nxt][4096 + ldst]);
        }
        bar();
        __builtin_amdgcn_s_setprio(1);
#pragma unroll
        for (int m = 0; m < 4; ++m)
#pragma unroll
            for (int n = 0; n < 2; ++n)
#pragma unroll
                for (int k = 0; k < 2; ++k)
                    acc[m][n + 2] = __builtin_amdgcn_mfma_f32_16x16x32_bf16(af[m][k], bm1[n][k], acc[m][n + 2], 0, 0, 0);
        __builtin_amdgcn_s_setprio(0);
        if (pf) asm volatile("s_waitcnt vmcnt(2)" ::: "memory");   // leave next Bm in flight
        bar();
    }
#undef FRAG

    // fused second backsub stage: rowpart[i] = sum_j v*m[j] + s*d[j]*|v|
    float s = chain ? 1.f : -1.f;
    float rowpart[4][4];
#pragma unroll
    for (int m = 0; m < 4; ++m)
#pragma unroll
        for (int r = 0; r < 4; ++r) rowpart[m][r] = 0.f;

    int jbase = ct * 128 + wc * 64;
#pragma unroll
    for (int n = 0; n < 4; ++n) {
        int j = jbase + n * 16 + la;
        float l0 = lb0[j], u0 = ub0[j];
        float mj = 0.5f * (l0 + u0);
        float sdj = s * 0.5f * (u0 - l0);
#pragma unroll
        for (int m = 0; m < 4; ++m)
#pragma unroll
            for (int r = 0; r < 4; ++r) {
                float v = acc[m][n][r];
                rowpart[m][r] += v * mj + sdj * fabsf(v);
            }
    }
    long long rowg = (long long)chain * N4K + (rt & 15) * 256 + wr * 64 + kq * 4;
#pragma unroll
    for (int m = 0; m < 4; ++m)
#pragma unroll
        for (int r = 0; r < 4; ++r) {
            float v = rowpart[m][r];
            v += __shfl_xor(v, 1);
            v += __shfl_xor(v, 2);
            v += __shfl_xor(v, 4);
            v += __shfl_xor(v, 8);
            if (la == 0) atomicAdd(&prev[rowg + m * 16 + r], v);
        }
}

// ---- epilogue: PReLU relaxation, scatter diag + bias col
__global__ __launch_bounds__(256) void epilogue(const float* __restrict__ prev,
                                                const float* __restrict__ alphas,
                                                float* __restrict__ out) {
    int i = blockIdx.x * 256 + threadIdx.x;
    if (i >= N4K) return;
    float lb = prev[i], ub = prev[N4K + i];
    float a = fminf(fmaxf(alphas[i], 0.f), 1.f);
    if (lb > 0.f) a = 1.f;
    if (ub <= 0.f) a = 0.f;
    float slope = ub / (ub - lb + FLT_EPSILON);
    if (lb > 0.f) slope = 1.f;
    if (ub < 0.f) slope = 0.f;
    float bias = -lb * slope;
    if (lb > 0.f || ub < 0.f) bias = 0.f;
    long long P = NP1, half = (long long)N4K * NP1;
    out[(long long)i * P + i] = a;
    out[half + (long long)i * P + i] = slope;
    out[half + (long long)i * P + 4096] = bias;
}

extern "C" void kernel_launch(void* const* d_in, const int* in_sizes, int n_in,
                              void* d_out, int out_size, void* d_ws, size_t ws_size,
                              hipStream_t stream) {
    const float* lb0    = (const float*)d_in[0];
    const float* ub0    = (const float*)d_in[1];
    const float* W1lb   = (const float*)d_in[2];
    const float* W1ub   = (const float*)d_in[3];
    const float* W2lb   = (const float*)d_in[4];
    const float* W2ub   = (const float*)d_in[5];
    const float* alphas = (const float*)d_in[6];

    char* ws = (char*)d_ws;
    float* prev = (float*)ws;                                    // 32768 B
    float* mb   = (float*)(ws + 32768);                          // 16384 B
    float* db   = (float*)(ws + 49152);                          // 16384 B
    unsigned short* Abf = (unsigned short*)(ws + 65536);         // 64 MiB
    unsigned short* Bmt = (unsigned short*)(ws + 65536 + 67108864);   // 32 MiB
    unsigned short* Bdt = (unsigned short*)(ws + 65536 + 100663296);  // 32 MiB
    size_t need = 65536ULL + 67108864ULL + 2ULL * 33554432ULL;   // ~128 MiB
    if (ws_size < need) return;

    (void)hipMemsetAsync(d_out, 0, (size_t)out_size * 4, stream);

    prep_mbdb<<<16, 256, 0, stream>>>(W1lb, W1ub, mb, db);
    prep_A2<<<8192, 256, 0, stream>>>(W2lb, W2ub, mb, db, Abf, prev);
    prep_B<<<dim3(64, 64), 256, 0, stream>>>(W1lb, W1ub, Bmt, Bdt);
    gemm_fused<<<1024, 512, 0, stream>>>(Abf, Bmt, Bdt, lb0, ub0, prev);
    epilogue<<<16, 256, 0, stream>>>(prev, alphas, (float*)d_out);
}

// Round 4
// 668.754 us; speedup vs baseline: 1.3465x; 1.0713x over previous
//
#include <hip/hip_runtime.h>
#include <float.h>

#define N4K 4096
#define NP1 4097

typedef __attribute__((ext_vector_type(4))) float f32x4;
typedef __attribute__((ext_vector_type(8))) short bf16x8;

__device__ __forceinline__ unsigned short f2bf(float x) {
    union { float f; unsigned int u; } v; v.f = x;
    unsigned int r = v.u + 0x7FFFu + ((v.u >> 16) & 1u);   // round-nearest-even
    return (unsigned short)(r >> 16);
}

__device__ __forceinline__ void gload_lds16(const void* g, void* l) {
    __builtin_amdgcn_global_load_lds(
        (const __attribute__((address_space(1))) unsigned int*)g,
        (__attribute__((address_space(3))) unsigned int*)l,
        16, 0, 0);
}

__device__ __forceinline__ void bar() {
    asm volatile("" ::: "memory");
    __builtin_amdgcn_s_barrier();
    asm volatile("" ::: "memory");
}

// ---- prep: W2 row -> bf16 cast + fused bias-matvec
__global__ __launch_bounds__(256) void prep_A2(const float* __restrict__ W2lb,
                                               const float* __restrict__ W2ub,
                                               const float* __restrict__ mb,
                                               const float* __restrict__ db,
                                               unsigned short* __restrict__ Abf,
                                               float* __restrict__ bias_part) {
    int b = blockIdx.x;                 // 0..8191
    int chain = b >> 12, i = b & 4095;
    const float* row = (chain ? W2ub : W2lb) + (long long)i * NP1;
    unsigned short* abf_row = Abf + ((long long)chain << 24) + (long long)i * N4K;
    float s = chain ? 1.f : -1.f;
    float part = 0.f;
#pragma unroll 4
    for (int p = 0; p < 16; ++p) {
        int k = threadIdx.x + p * 256;
        float wv = row[k];
        abf_row[k] = f2bf(wv);
        part += wv * mb[k] + s * db[k] * fabsf(wv);
    }
    __shared__ float red[4];
#pragma unroll
    for (int off = 32; off; off >>= 1) part += __shfl_down(part, off);
    if ((threadIdx.x & 63) == 0) red[threadIdx.x >> 6] = part;
    __syncthreads();
    if (threadIdx.x == 0)
        bias_part[b] = red[0] + red[1] + red[2] + red[3] + row[4096];
}

// ---- prep: build M^T, D^T bf16 [4096 j][4096 k] via LDS tile transpose
__global__ __launch_bounds__(256) void prep_B(const float* __restrict__ W1lb,
                                              const float* __restrict__ W1ub,
                                              unsigned short* __restrict__ Bmt,
                                              unsigned short* __restrict__ Bdt) {
    __shared__ unsigned short Lm[64 * 65];
    __shared__ unsigned short Ld[64 * 65];
    int j0 = blockIdx.x * 64, k0 = blockIdx.y * 64;
    int t = threadIdx.x;
    int jj = t & 63, kkb = t >> 6;
#pragma unroll 4
    for (int p = 0; p < 16; ++p) {
        int kk = kkb + p * 4;
        long long off = (long long)(k0 + kk) * NP1 + j0 + jj;
        float l = W1lb[off], u = W1ub[off];
        Lm[kk * 65 + jj] = f2bf(0.5f * (l + u));
        Ld[kk * 65 + jj] = f2bf(0.5f * (u - l));
    }
    __syncthreads();
#pragma unroll
    for (int p = 0; p < 2; ++p) {
        int jl = p * 32 + (t >> 3);
        int kl = (t & 7) * 8;
        bf16x8 vm, vd;
#pragma unroll
        for (int i = 0; i < 8; ++i) {
            vm[i] = (short)Lm[(kl + i) * 65 + jl];
            vd[i] = (short)Ld[(kl + i) * 65 + jl];
        }
        *(bf16x8*)&Bmt[(long long)(j0 + jl) * N4K + k0 + kl] = vm;
        *(bf16x8*)&Bdt[(long long)(j0 + jl) * N4K + k0 + kl] = vd;
    }
}

// ---- prep: bias column of W1 -> mb, db (fp32)
__global__ __launch_bounds__(256) void prep_mbdb(const float* __restrict__ W1lb,
                                                 const float* __restrict__ W1ub,
                                                 float* __restrict__ mb,
                                                 float* __restrict__ db) {
    int k = blockIdx.x * 256 + threadIdx.x;
    if (k < N4K) {
        float l = W1lb[(long long)k * NP1 + 4096];
        float u = W1ub[(long long)k * NP1 + 4096];
        mb[k] = 0.5f * (l + u);
        db[k] = 0.5f * (u - l);
    }
}

// ---- fused GEMM: 256x128 tile, BK=64, k-split phases, 1 barrier/phase, partial stores
__global__ __launch_bounds__(512, 2) void gemm_fused(const unsigned short* __restrict__ Abf,
                                                     const unsigned short* __restrict__ Bmt,
                                                     const unsigned short* __restrict__ Bdt,
                                                     const float* __restrict__ lb0,
                                                     const float* __restrict__ ub0,
                                                     float* __restrict__ pp) {
    __shared__ unsigned short As[2][16384];   // 256x64 bf16, dbuf
    __shared__ unsigned short Bms[2][8192];   // 128x64
    __shared__ unsigned short Bds[2][8192];

    int wg = blockIdx.x;
    int swz = (wg & 7) * 128 + (wg >> 3);     // XCD-aware bijective (1024 % 8 == 0)
    int rt = swz & 31;
    int ct = swz >> 5;

    int chain = rt >> 4;
    const unsigned short* Aptr = Abf + ((long long)chain << 24) + (long long)(rt & 15) * 256 * N4K;
    const unsigned short* Bmp = Bmt + (long long)ct * 128 * N4K;
    const unsigned short* Bdp = Bdt + (long long)ct * 128 * N4K;

    int tid = threadIdx.x;
    int lane = tid & 63, w = tid >> 6;
    int wr = w >> 1, wc = w & 1;              // 4M x 2N waves, 64x64 per wave
    int la = lane & 15, kq = lane >> 4;
    int x7 = la & 7;

    int srow = tid >> 3;
    int sce = ((tid & 7) ^ (srow & 7)) << 3;  // inverse-swizzled global col
    const unsigned short* aS = Aptr + (long long)srow * N4K + sce;
    const unsigned short* mS = Bmp + (long long)srow * N4K + sce;
    const unsigned short* dS = Bdp + (long long)srow * N4K + sce;
    const long long R64 = 64LL * N4K;
    unsigned ldst = w * 512;

    int arow = wr * 64 + la;
    int brow = wc * 64 + la;

    f32x4 acc[4][4];
#pragma unroll
    for (int m = 0; m < 4; ++m)
#pragma unroll
        for (int n = 0; n < 4; ++n) acc[m][n] = (f32x4){0.f, 0.f, 0.f, 0.f};

    // prologue: stage tile 0 fully, drain, barrier
#pragma unroll
    for (int q = 0; q < 4; ++q) gload_lds16(aS + q * R64, &As[0][q * 4096 + ldst]);
#pragma unroll
    for (int q = 0; q < 2; ++q) gload_lds16(mS + q * R64, &Bms[0][q * 4096 + ldst]);
#pragma unroll
    for (int q = 0; q < 2; ++q) gload_lds16(dS + q * R64, &Bds[0][q * 4096 + ldst]);
    asm volatile("s_waitcnt vmcnt(0)" ::: "memory");
    bar();

#define FRAG(arr, cur, rb, f, k) \
    (*(const bf16x8*)&arr[cur][((rb) + (f) * 16) * 64 + ((((k) * 4 + kq) ^ x7) * 8)])

#pragma unroll 1
    for (int t = 0; t < 64; ++t) {
        const int cur = t & 1, nxt = cur ^ 1;
        const int k0n = (t + 1) * 64;
        const bool pf = (t < 63);

        bf16x8 a0[4], a1[4], ax0[4], ax1[4], bd0[4], bd1[4], bm0[4], bm1[4];

        // ===== phase 0: read A(k0)+Bd(k0); stage Bd'; MFMA |A|k0 . Bd k0
#pragma unroll
        for (int m = 0; m < 4; ++m) a0[m] = FRAG(As, cur, arow, m, 0);
#pragma unroll
        for (int n = 0; n < 4; ++n) bd0[n] = FRAG(Bds, cur, brow, n, 0);
        if (pf) {
            gload_lds16(dS + k0n, &Bds[nxt][ldst]);
            gload_lds16(dS + R64 + k0n, &Bds[nxt][4096 + ldst]);
        }
#pragma unroll
        for (int m = 0; m < 4; ++m)
            ax0[m] = chain ? (a0[m] & (short)0x7FFF) : (a0[m] | (short)0x8000);
        __builtin_amdgcn_s_setprio(1);
#pragma unroll
        for (int m = 0; m < 4; ++m)
#pragma unroll
            for (int n = 0; n < 4; ++n)
                acc[m][n] = __builtin_amdgcn_mfma_f32_16x16x32_bf16(ax0[m], bd0[n], acc[m][n], 0, 0, 0);
        __builtin_amdgcn_s_setprio(0);
        bar();

        // ===== phase 1: read A(k1)+Bd(k1); stage A'lo; MFMA; drain prev Bm'
#pragma unroll
        for (int m = 0; m < 4; ++m) a1[m] = FRAG(As, cur, arow, m, 1);
#pragma unroll
        for (int n = 0; n < 4; ++n) bd1[n] = FRAG(Bds, cur, brow, n, 1);
        if (pf) {
            gload_lds16(aS + k0n, &As[nxt][ldst]);
            gload_lds16(aS + R64 + k0n, &As[nxt][4096 + ldst]);
        }
#pragma unroll
        for (int m = 0; m < 4; ++m)
            ax1[m] = chain ? (a1[m] & (short)0x7FFF) : (a1[m] | (short)0x8000);
        __builtin_amdgcn_s_setprio(1);
#pragma unroll
        for (int m = 0; m < 4; ++m)
#pragma unroll
            for (int n = 0; n < 4; ++n)
                acc[m][n] = __builtin_amdgcn_mfma_f32_16x16x32_bf16(ax1[m], bd1[n], acc[m][n], 0, 0, 0);
        __builtin_amdgcn_s_setprio(0);
        if (pf) asm volatile("s_waitcnt vmcnt(4)" ::: "memory");
        else    asm volatile("s_waitcnt vmcnt(0)" ::: "memory");
        bar();

        // ===== phase 2: read Bm(k0); stage A'hi; MFMA A k0 . Bm k0 (A in regs)
#pragma unroll
        for (int n = 0; n < 4; ++n) bm0[n] = FRAG(Bms, cur, brow, n, 0);
        if (pf) {
            gload_lds16(aS + 2 * R64 + k0n, &As[nxt][8192 + ldst]);
            gload_lds16(aS + 3 * R64 + k0n, &As[nxt][12288 + ldst]);
        }
        __builtin_amdgcn_s_setprio(1);
#pragma unroll
        for (int m = 0; m < 4; ++m)
#pragma unroll
            for (int n = 0; n < 4; ++n)
                acc[m][n] = __builtin_amdgcn_mfma_f32_16x16x32_bf16(a0[m], bm0[n], acc[m][n], 0, 0, 0);
        __builtin_amdgcn_s_setprio(0);
        bar();

        // ===== phase 3: read Bm(k1); stage Bm'; MFMA A k1 . Bm k1; boundary drain
#pragma unroll
        for (int n = 0; n < 4; ++n) bm1[n] = FRAG(Bms, cur, brow, n, 1);
        if (pf) {
            gload_lds16(mS + k0n, &Bms[nxt][ldst]);
            gload_lds16(mS + R64 + k0n, &Bms[nxt][4096 + ldst]);
        }
        __builtin_amdgcn_s_setprio(1);
#pragma unroll
        for (int m = 0; m < 4; ++m)
#pragma unroll
            for (int n = 0; n < 4; ++n)
                acc[m][n] = __builtin_amdgcn_mfma_f32_16x16x32_bf16(a1[m], bm1[n], acc[m][n], 0, 0, 0);
        __builtin_amdgcn_s_setprio(0);
        if (pf) asm volatile("s_waitcnt vmcnt(2)" ::: "memory");
        bar();
    }
#undef FRAG

    // fused second backsub stage -> uncontended partial stores
    float s = chain ? 1.f : -1.f;
    float rowpart[4][4];
#pragma unroll
    for (int m = 0; m < 4; ++m)
#pragma unroll
        for (int r = 0; r < 4; ++r) rowpart[m][r] = 0.f;

    int jbase = ct * 128 + wc * 64;
#pragma unroll
    for (int n = 0; n < 4; ++n) {
        int j = jbase + n * 16 + la;
        float l0 = lb0[j], u0 = ub0[j];
        float mj = 0.5f * (l0 + u0);
        float sdj = s * 0.5f * (u0 - l0);
#pragma unroll
        for (int m = 0; m < 4; ++m)
#pragma unroll
            for (int r = 0; r < 4; ++r) {
                float v = acc[m][n][r];
                rowpart[m][r] += v * mj + sdj * fabsf(v);
            }
    }
    long long rowg = (long long)chain * N4K + (rt & 15) * 256 + wr * 64 + kq * 4;
    long long slice = (long long)(ct * 2 + wc) * 8192;
#pragma unroll
    for (int m = 0; m < 4; ++m)
#pragma unroll
        for (int r = 0; r < 4; ++r) {
            float v = rowpart[m][r];
            v += __shfl_xor(v, 1);
            v += __shfl_xor(v, 2);
            v += __shfl_xor(v, 4);
            v += __shfl_xor(v, 8);
            if (la == 0) pp[slice + rowg + m * 16 + r] = v;
        }
}

// ---- reduce 64 partial slices + bias -> prev[8192]
__global__ __launch_bounds__(256) void reduce_pp(const float* __restrict__ pp,
                                                 const float* __restrict__ bias_part,
                                                 float* __restrict__ prev) {
    int j = blockIdx.x * 256 + threadIdx.x;
    float s = bias_part[j];
#pragma unroll 8
    for (int c = 0; c < 64; ++c) s += pp[(long long)c * 8192 + j];
    prev[j] = s;
}

// ---- epilogue: PReLU relaxation, scatter diag + bias col
__global__ __launch_bounds__(256) void epilogue(const float* __restrict__ prev,
                                                const float* __restrict__ alphas,
                                                float* __restrict__ out) {
    int i = blockIdx.x * 256 + threadIdx.x;
    if (i >= N4K) return;
    float lb = prev[i], ub = prev[N4K + i];
    float a = fminf(fmaxf(alphas[i], 0.f), 1.f);
    if (lb > 0.f) a = 1.f;
    if (ub <= 0.f) a = 0.f;
    float slope = ub / (ub - lb + FLT_EPSILON);
    if (lb > 0.f) slope = 1.f;
    if (ub < 0.f) slope = 0.f;
    float bias = -lb * slope;
    if (lb > 0.f || ub < 0.f) bias = 0.f;
    long long P = NP1, half = (long long)N4K * NP1;
    out[(long long)i * P + i] = a;
    out[half + (long long)i * P + i] = slope;
    out[half + (long long)i * P + 4096] = bias;
}

extern "C" void kernel_launch(void* const* d_in, const int* in_sizes, int n_in,
                              void* d_out, int out_size, void* d_ws, size_t ws_size,
                              hipStream_t stream) {
    const float* lb0    = (const float*)d_in[0];
    const float* ub0    = (const float*)d_in[1];
    const float* W1lb   = (const float*)d_in[2];
    const float* W1ub   = (const float*)d_in[3];
    const float* W2lb   = (const float*)d_in[4];
    const float* W2ub   = (const float*)d_in[5];
    const float* alphas = (const float*)d_in[6];

    char* ws = (char*)d_ws;
    float* bias_part = (float*)ws;                               // 32768 B
    float* mb   = (float*)(ws + 32768);                          // 16384 B
    float* db   = (float*)(ws + 49152);                          // 16384 B
    float* prev = (float*)(ws + 32768);                          // reuses mb/db after they die
    unsigned short* Abf = (unsigned short*)(ws + 65536);         // 64 MiB
    unsigned short* Bmt = (unsigned short*)(ws + 65536 + 67108864);   // 32 MiB
    unsigned short* Bdt = (unsigned short*)(ws + 65536 + 100663296);  // 32 MiB
    size_t need = 65536ULL + 67108864ULL + 2ULL * 33554432ULL;
    if (ws_size < need) return;

    float* pp = (float*)d_out;   // 2 MiB scratch inside output, re-zeroed below

    (void)hipMemsetAsync(d_out, 0, (size_t)out_size * 4, stream);

    prep_mbdb<<<16, 256, 0, stream>>>(W1lb, W1ub, mb, db);
    prep_A2<<<8192, 256, 0, stream>>>(W2lb, W2ub, mb, db, Abf, bias_part);
    prep_B<<<dim3(64, 64), 256, 0, stream>>>(W1lb, W1ub, Bmt, Bdt);
    gemm_fused<<<1024, 512, 0, stream>>>(Abf, Bmt, Bdt, lb0, ub0, pp);
    reduce_pp<<<32, 256, 0, stream>>>(pp, bias_part, prev);
    (void)hipMemsetAsync(d_out, 0, 64 * 8192 * 4, stream);   // clear pp scratch
    epilogue<<<16, 256, 0, stream>>>(prev, alphas, (float*)d_out);
}